// Round 1
// baseline (35.021 us; speedup 1.0000x reference)
//
#include <hip/hip_runtime.h>
#include <math.h>

#define N_PTS 16384
#define D_DIM 128
#define C_CLS 10
#define K_MIX 16

constexpr float EPSF   = 1.1920928955078125e-07f;  // np.finfo(float32).eps
constexpr float LOG2PI = 1.8378770664093453f;
constexpr float LN2F   = 0.6931471805599453f;

__device__ __forceinline__ float softplusf(float x) {
    if (x > 20.f)  return x;
    if (x < -20.f) return expf(x);
    return log1pf(expf(x));
}
__device__ __forceinline__ float ndtrf(float x) {
    return 0.5f * erfcf(-x * 0.70710678118654752440f);
}

// ---------------------------------------------------------------------------
// K1: per-(c,k) precompute. 160 blocks x 64 threads, one wave per (c,k).
// Writes transposed params muT/isT/loT/upT [c][d][k] and
// Ack[c*K+k] = -log_norm - sum_d log(scale) - 0.5*D*LOG2PI
// ---------------------------------------------------------------------------
__global__ __launch_bounds__(64) void k_params(
    const float* __restrict__ mu, const float* __restrict__ lower,
    const float* __restrict__ upper, const float* __restrict__ sigma,
    float* __restrict__ muT, float* __restrict__ isT,
    float* __restrict__ loT, float* __restrict__ upT,
    float* __restrict__ Ack) {
    int b = blockIdx.x;               // c*K + k
    int c = b / K_MIX, k = b % K_MIX;
    int lane = threadIdx.x;           // 0..63
    float ls_sum = 0.f;
    float zprod  = 1.f;
    #pragma unroll
    for (int half = 0; half < 2; ++half) {
        int d  = lane + 64 * half;
        int gi = (c * K_MIX + k) * D_DIM + d;
        float m  = mu[gi], lo = lower[gi], up = upper[gi], sg = sigma[gi];
        float sc = EPSF + softplusf(sg);
        float is = 1.f / sc;
        int ti = c * (D_DIM * K_MIX) + d * K_MIX + k;
        muT[ti] = m; isT[ti] = is; loT[ti] = lo; upT[ti] = up;
        ls_sum += logf(sc);
        float z = ndtrf((up - m) * is) - ndtrf((lo - m) * is);
        zprod *= z;
    }
    #pragma unroll
    for (int off = 1; off < 64; off <<= 1) {
        ls_sum += __shfl_xor(ls_sum, off);
        zprod  *= __shfl_xor(zprod, off);
    }
    if (lane == 0) {
        float log_norm = logf(zprod + EPSF);
        Ack[b] = -log_norm - ls_sum - 0.5f * (float)D_DIM * LOG2PI;
    }
}

// ---------------------------------------------------------------------------
// K1b: counts (deterministic int LDS hist) + log_softmax fold into const_ck.
// 1 block x 256 threads.
// ---------------------------------------------------------------------------
__global__ __launch_bounds__(256) void k_const(
    const float* __restrict__ logits, const int* __restrict__ y,
    const float* __restrict__ Ack,
    float* __restrict__ const_ck, int* __restrict__ counts) {
    __shared__ int hist[C_CLS];
    int t = threadIdx.x;
    if (t < C_CLS) hist[t] = 0;
    __syncthreads();
    for (int i = t; i < N_PTS; i += 256) atomicAdd(&hist[y[i]], 1);
    __syncthreads();
    if (t < C_CLS) {
        int c = t;
        counts[c] = hist[c];
        float mx = -1e30f;
        for (int k = 0; k < K_MIX; ++k) mx = fmaxf(mx, logits[c * K_MIX + k]);
        float se = 0.f;
        for (int k = 0; k < K_MIX; ++k) se += expf(logits[c * K_MIX + k] - mx);
        float lse = mx + logf(se);
        for (int k = 0; k < K_MIX; ++k)
            const_ck[c * K_MIX + k] = logits[c * K_MIX + k] - lse + Ack[c * K_MIX + k];
    }
}

// ---------------------------------------------------------------------------
// K2: main. 1024 blocks x 256 threads; thread = (n_local, k); 16 n per block.
// X rows staged in LDS (pad to 132 -> conflict-free broadcast reads).
// Emits one partial per block: sum_n sum_k resp*log_pdf / (counts[c]*K).
// ---------------------------------------------------------------------------
__global__ __launch_bounds__(256) void k_main(
    const float* __restrict__ X, const int* __restrict__ y,
    const float* __restrict__ resp,
    const float* __restrict__ muT, const float* __restrict__ isT,
    const float* __restrict__ loT, const float* __restrict__ upT,
    const float* __restrict__ const_ck, const int* __restrict__ counts,
    const float* __restrict__ etap, float* __restrict__ blockPartials) {
    __shared__ float xs[16][132];
    __shared__ float sums[16];
    int t  = threadIdx.x;
    int n0 = blockIdx.x * 16;

    // stage 16 rows of X (2048 floats) via float4, coalesced
    #pragma unroll
    for (int i = 0; i < 2; ++i) {
        int j  = t * 2 + i;              // 0..511 float4 slots
        int r  = j >> 5, c4 = j & 31;
        float4 v = *reinterpret_cast<const float4*>(X + (size_t)(n0 + r) * D_DIM + c4 * 4);
        xs[r][c4 * 4 + 0] = v.x; xs[r][c4 * 4 + 1] = v.y;
        xs[r][c4 * 4 + 2] = v.z; xs[r][c4 * 4 + 3] = v.w;
    }
    __syncthreads();

    int k  = t & 15;
    int nl = (t >> 4) & 3;
    int w  = t >> 6;
    int n_local = w * 4 + nl;
    int n  = n0 + n_local;
    int c  = y[n];

    const float* mp = muT + (size_t)c * (D_DIM * K_MIX) + k;
    const float* sp = isT + (size_t)c * (D_DIM * K_MIX) + k;

    float acc = 0.f;
    #pragma unroll 4
    for (int d = 0; d < D_DIM; ++d) {
        float x  = xs[n_local][d];
        float zd = (x - mp[d * K_MIX]) * sp[d * K_MIX];
        acc = fmaf(zd, zd, acc);
    }

    float eta = etap[0];
    float lp;
    if (eta == 0.f) {
        lp = -2.f * (float)D_DIM * LN2F;   // softplus(0)=ln2, both terms
    } else {
        lp = 0.f;
        const float* lo = loT + (size_t)c * (D_DIM * K_MIX) + k;
        const float* up = upT + (size_t)c * (D_DIM * K_MIX) + k;
        for (int d = 0; d < D_DIM; ++d) {
            float x = xs[n_local][d];
            lp -= softplusf(-eta * (x - lo[d * K_MIX]))
                + softplusf(-eta * (up[d * K_MIX] - x));
        }
    }

    float r_ = resp[((size_t)c * N_PTS + n) * K_MIX + k];
    float v  = r_ * (const_ck[c * K_MIX + k] + lp - 0.5f * acc);
    v *= 1.f / ((float)counts[c] * (float)K_MIX);

    // sum over the 16 k-lanes of this n (fixed-order tree, deterministic)
    v += __shfl_xor(v, 1);
    v += __shfl_xor(v, 2);
    v += __shfl_xor(v, 4);
    v += __shfl_xor(v, 8);
    if (k == 0) sums[n_local] = v;
    __syncthreads();
    if (t == 0) {
        float s = 0.f;
        #pragma unroll
        for (int i = 0; i < 16; ++i) s += sums[i];
        blockPartials[blockIdx.x] = s;
    }
}

// ---------------------------------------------------------------------------
// K3: reduce 1024 block partials -> loss (fixed-order, deterministic)
// ---------------------------------------------------------------------------
__global__ __launch_bounds__(256) void k_final(
    const float* __restrict__ blockPartials, float* __restrict__ out) {
    __shared__ float red[256];
    int t = threadIdx.x;
    float s = 0.f;
    for (int i = t; i < 1024; i += 256) s += blockPartials[i];
    red[t] = s;
    __syncthreads();
    for (int off = 128; off > 0; off >>= 1) {
        if (t < off) red[t] += red[t + off];
        __syncthreads();
    }
    if (t == 0) out[0] = -red[0];
}

// ---------------------------------------------------------------------------
extern "C" void kernel_launch(void* const* d_in, const int* in_sizes, int n_in,
                              void* d_out, int out_size, void* d_ws, size_t ws_size,
                              hipStream_t stream) {
    const float* X      = (const float*)d_in[0];
    const int*   y      = (const int*)  d_in[1];
    const float* resp   = (const float*)d_in[2];
    const float* mu     = (const float*)d_in[3];
    const float* lower  = (const float*)d_in[4];
    const float* upper  = (const float*)d_in[5];
    const float* sigma  = (const float*)d_in[6];
    const float* logits = (const float*)d_in[7];
    const float* eta    = (const float*)d_in[8];
    float* out = (float*)d_out;

    char* ws = (char*)d_ws;
    size_t off = 0;
    auto alloc = [&](size_t bytes) {
        void* p = ws + off;
        off += (bytes + 255) & ~size_t(255);
        return p;
    };
    const size_t PARAM = (size_t)C_CLS * D_DIM * K_MIX * sizeof(float); // 80 KiB
    float* muT      = (float*)alloc(PARAM);
    float* isT      = (float*)alloc(PARAM);
    float* loT      = (float*)alloc(PARAM);
    float* upT      = (float*)alloc(PARAM);
    float* Ack      = (float*)alloc(C_CLS * K_MIX * sizeof(float));
    float* const_ck = (float*)alloc(C_CLS * K_MIX * sizeof(float));
    int*   counts   = (int*)  alloc(C_CLS * sizeof(int));
    float* partials = (float*)alloc((N_PTS / 16) * sizeof(float));

    k_params<<<C_CLS * K_MIX, 64, 0, stream>>>(mu, lower, upper, sigma,
                                               muT, isT, loT, upT, Ack);
    k_const<<<1, 256, 0, stream>>>(logits, y, Ack, const_ck, counts);
    k_main<<<N_PTS / 16, 256, 0, stream>>>(X, y, resp, muT, isT, loT, upT,
                                           const_ck, counts, eta, partials);
    k_final<<<1, 256, 0, stream>>>(partials, out);
}

// Round 2
// 34.530 us; speedup vs baseline: 1.0142x; 1.0142x over previous
//
#include <hip/hip_runtime.h>
#include <math.h>

#define N_PTS 16384
#define D_DIM 128
#define C_CLS 10
#define K_MIX 16
#define HIST_BLOCKS 64   // 64 blocks x 256 pts
#define MAIN_BPC 32      // main blocks per class

constexpr float EPSF   = 1.1920928955078125e-07f;
constexpr float LOG2PI = 1.8378770664093453f;
constexpr float LN2F   = 0.6931471805599453f;

__device__ __forceinline__ float softplusf(float x) {
    if (x > 20.f)  return x;
    if (x < -20.f) return expf(x);
    return log1pf(expf(x));
}
__device__ __forceinline__ float ndtrf(float x) {
    return 0.5f * erfcf(-x * 0.70710678118654752440f);
}

// ---------------------------------------------------------------------------
// K1: blocks [0,160): per-(c,k) params -> abT(float2)[c][d][k], loT/upT, Ack.
//     blocks [160,224): per-256-pt class histogram -> blockCnt[h][c].
// ---------------------------------------------------------------------------
__global__ __launch_bounds__(256) void k_prep(
    const float* __restrict__ mu, const float* __restrict__ lower,
    const float* __restrict__ upper, const float* __restrict__ sigma,
    const int* __restrict__ y,
    float2* __restrict__ abT, float* __restrict__ loT, float* __restrict__ upT,
    float* __restrict__ Ack, int* __restrict__ blockCnt) {
    int b = blockIdx.x, t = threadIdx.x;
    if (b < C_CLS * K_MIX) {
        int c = b / K_MIX, k = b % K_MIX;
        __shared__ float rs0[256], rs1[256], rp[256];
        float logsc = 0.f, mu2 = 0.f, zz = 1.f;
        if (t < D_DIM) {
            int gi = b * D_DIM + t;
            float m = mu[gi], lo = lower[gi], up = upper[gi], sg = sigma[gi];
            float sc = EPSF + softplusf(sg);
            float is = 1.f / sc;
            int ti = (c * D_DIM + t) * K_MIX + k;
            abT[ti] = make_float2(is * is, 2.f * m * is * is);
            loT[ti] = lo; upT[ti] = up;
            logsc = logf(sc);
            mu2   = m * m * is * is;
            zz    = ndtrf((up - m) * is) - ndtrf((lo - m) * is);
        }
        rs0[t] = logsc; rs1[t] = mu2; rp[t] = zz;
        __syncthreads();
        for (int off = 128; off > 0; off >>= 1) {
            if (t < off) { rs0[t] += rs0[t+off]; rs1[t] += rs1[t+off]; rp[t] *= rp[t+off]; }
            __syncthreads();
        }
        if (t == 0) {
            float log_norm = logf(rp[0] + EPSF);
            Ack[b] = -log_norm - rs0[0] - 0.5f * (float)D_DIM * LOG2PI - 0.5f * rs1[0];
        }
    } else {
        int h = b - C_CLS * K_MIX;
        __shared__ int hist[C_CLS];
        if (t < C_CLS) hist[t] = 0;
        __syncthreads();
        int c = y[h * 256 + t];
        int lane = t & 63;
        for (int cc = 0; cc < C_CLS; ++cc) {
            unsigned long long m = __ballot(c == cc);
            if (lane == 0 && m) atomicAdd(&hist[cc], __popcll(m));
        }
        __syncthreads();
        if (t < C_CLS) blockCnt[h * C_CLS + t] = hist[t];
    }
}

// ---------------------------------------------------------------------------
// K2: stable counting-sort scatter (deterministic) + const_ck/counts (block 0)
// ---------------------------------------------------------------------------
__global__ __launch_bounds__(256) void k_scatter(
    const int* __restrict__ y, const int* __restrict__ blockCnt,
    const float* __restrict__ logits, const float* __restrict__ Ack,
    int* __restrict__ idxSorted, int* __restrict__ classOff,
    float* __restrict__ invden, float* __restrict__ const_ck) {
    __shared__ int sCnt[HIST_BLOCKS * C_CLS];
    __shared__ int sClassOff[C_CLS + 1];
    __shared__ int myOff[C_CLS];
    __shared__ int wcnt[4][C_CLS];
    __shared__ int wbase[4][C_CLS];
    int h = blockIdx.x, t = threadIdx.x;
    for (int i = t; i < HIST_BLOCKS * C_CLS; i += 256) sCnt[i] = blockCnt[i];
    __syncthreads();
    if (t == 0) {
        int acc = 0;
        for (int c = 0; c < C_CLS; ++c) {
            sClassOff[c] = acc;
            int s = 0;
            for (int hh = 0; hh < HIST_BLOCKS; ++hh) s += sCnt[hh * C_CLS + c];
            acc += s;
        }
        sClassOff[C_CLS] = acc;
    }
    __syncthreads();
    if (t < C_CLS) {
        int s = sClassOff[t];
        for (int hh = 0; hh < h; ++hh) s += sCnt[hh * C_CLS + t];
        myOff[t] = s;
    }
    __syncthreads();
    int n = h * 256 + t;
    int c = y[n];
    int w = t >> 6, lane = t & 63;
    int rank = 0;
    for (int cc = 0; cc < C_CLS; ++cc) {
        unsigned long long m = __ballot(c == cc);
        if (c == cc) rank = __popcll(m & ((1ull << lane) - 1ull));
        if (lane == 0) wcnt[w][cc] = __popcll(m);
    }
    __syncthreads();
    if (t < 4 * C_CLS) {
        int ww = t / C_CLS, cc = t % C_CLS;
        int s = myOff[cc];
        for (int w2 = 0; w2 < ww; ++w2) s += wcnt[w2][cc];
        wbase[ww][cc] = s;
    }
    __syncthreads();
    idxSorted[wbase[w][c] + rank] = n;

    if (h == 0) {
        __shared__ float lse[C_CLS];
        if (t < C_CLS) {
            float mx = -1e30f;
            for (int k = 0; k < K_MIX; ++k) mx = fmaxf(mx, logits[t * K_MIX + k]);
            float se = 0.f;
            for (int k = 0; k < K_MIX; ++k) se += expf(logits[t * K_MIX + k] - mx);
            lse[t] = mx + logf(se);
            int cnt = sClassOff[t + 1] - sClassOff[t];
            invden[t] = (cnt > 0) ? 1.f / ((float)cnt * (float)K_MIX) : 0.f;
        }
        if (t < C_CLS + 1) classOff[t] = sClassOff[t];
        __syncthreads();
        if (t < C_CLS * K_MIX) const_ck[t] = logits[t] - lse[t / K_MIX] + Ack[t];
    }
}

// ---------------------------------------------------------------------------
// K3: main. Grid = C*32 blocks, single-class per block. Wave = 16k x 4 dchunk.
// Params live in registers (a_[32], b_[32] per lane). One point per wave/iter.
// ---------------------------------------------------------------------------
__global__ __launch_bounds__(256) void k_main(
    const float* __restrict__ X, const float* __restrict__ resp,
    const float2* __restrict__ abT, const float* __restrict__ loT,
    const float* __restrict__ upT, const float* __restrict__ const_ck,
    const int* __restrict__ classOff, const float* __restrict__ invden,
    const int* __restrict__ idxSorted, const float* __restrict__ etap,
    float* __restrict__ partials) {
    int b = blockIdx.x;
    int c = b / MAIN_BPC, j = b % MAIN_BPC;
    int t = threadIdx.x;
    int w = t >> 6, lane = t & 63;
    int k = lane & 15, dc = lane >> 4;
    const int d0 = dc * 32;

    float a_[32], b_[32];
    const float2* ab = abT + (size_t)c * D_DIM * K_MIX + k;
    #pragma unroll
    for (int i = 0; i < 32; ++i) {
        float2 v = ab[(size_t)(d0 + i) * K_MIX];
        a_[i] = v.x; b_[i] = v.y;
    }
    float ck  = const_ck[c * K_MIX + k];
    float eta = etap[0];
    float inv = invden[c];
    int off = classOff[c];
    int cnt = classOff[c + 1] - off;
    const float lpconst = -2.f * (float)D_DIM * LN2F;

    float wsum = 0.f;
    for (int p = j * 4 + w; p < cnt; p += MAIN_BPC * 4) {
        int n = idxSorted[off + p];
        const float* xr = X + (size_t)n * D_DIM + d0;
        float acc = 0.f, lp = lpconst;
        if (eta == 0.f) {
            #pragma unroll
            for (int i4 = 0; i4 < 8; ++i4) {
                float4 xv = *reinterpret_cast<const float4*>(xr + i4 * 4);
                acc = fmaf(xv.x, fmaf(a_[i4*4+0], xv.x, -b_[i4*4+0]), acc);
                acc = fmaf(xv.y, fmaf(a_[i4*4+1], xv.y, -b_[i4*4+1]), acc);
                acc = fmaf(xv.z, fmaf(a_[i4*4+2], xv.z, -b_[i4*4+2]), acc);
                acc = fmaf(xv.w, fmaf(a_[i4*4+3], xv.w, -b_[i4*4+3]), acc);
            }
            acc += __shfl_xor(acc, 16);
            acc += __shfl_xor(acc, 32);
        } else {
            float lpp = 0.f;
            const float* lo = loT + (size_t)c * D_DIM * K_MIX + k;
            const float* up = upT + (size_t)c * D_DIM * K_MIX + k;
            #pragma unroll
            for (int i4 = 0; i4 < 8; ++i4) {
                float4 xv = *reinterpret_cast<const float4*>(xr + i4 * 4);
                float xs4[4] = {xv.x, xv.y, xv.z, xv.w};
                #pragma unroll
                for (int q = 0; q < 4; ++q) {
                    int i = i4 * 4 + q;
                    float x = xs4[q];
                    acc = fmaf(x, fmaf(a_[i], x, -b_[i]), acc);
                    float lov = lo[(size_t)(d0 + i) * K_MIX];
                    float upv = up[(size_t)(d0 + i) * K_MIX];
                    lpp -= softplusf(-eta * (x - lov)) + softplusf(-eta * (upv - x));
                }
            }
            acc += __shfl_xor(acc, 16); acc += __shfl_xor(acc, 32);
            lpp += __shfl_xor(lpp, 16); lpp += __shfl_xor(lpp, 32);
            lp = lpp;
        }
        float r = resp[((size_t)c * N_PTS + n) * K_MIX + k];
        float v = r * (ck + lp - 0.5f * acc) * inv;
        v += __shfl_xor(v, 1); v += __shfl_xor(v, 2);
        v += __shfl_xor(v, 4); v += __shfl_xor(v, 8);
        wsum += v;
    }
    __shared__ float ws[4];
    if (lane == 0) ws[w] = wsum;
    __syncthreads();
    if (t == 0) partials[b] = ws[0] + ws[1] + ws[2] + ws[3];
}

// ---------------------------------------------------------------------------
// K4: final fixed-order reduce
// ---------------------------------------------------------------------------
__global__ __launch_bounds__(256) void k_final(
    const float* __restrict__ partials, float* __restrict__ out) {
    __shared__ float red[256];
    int t = threadIdx.x;
    float s = 0.f;
    for (int i = t; i < C_CLS * MAIN_BPC; i += 256) s += partials[i];
    red[t] = s;
    __syncthreads();
    for (int off = 128; off > 0; off >>= 1) {
        if (t < off) red[t] += red[t + off];
        __syncthreads();
    }
    if (t == 0) out[0] = -red[0];
}

// ---------------------------------------------------------------------------
extern "C" void kernel_launch(void* const* d_in, const int* in_sizes, int n_in,
                              void* d_out, int out_size, void* d_ws, size_t ws_size,
                              hipStream_t stream) {
    const float* X      = (const float*)d_in[0];
    const int*   y      = (const int*)  d_in[1];
    const float* resp   = (const float*)d_in[2];
    const float* mu     = (const float*)d_in[3];
    const float* lower  = (const float*)d_in[4];
    const float* upper  = (const float*)d_in[5];
    const float* sigma  = (const float*)d_in[6];
    const float* logits = (const float*)d_in[7];
    const float* eta    = (const float*)d_in[8];
    float* out = (float*)d_out;

    char* ws = (char*)d_ws;
    size_t off = 0;
    auto alloc = [&](size_t bytes) {
        void* p = ws + off;
        off += (bytes + 255) & ~size_t(255);
        return p;
    };
    const size_t PE = (size_t)C_CLS * D_DIM * K_MIX;
    float2* abT      = (float2*)alloc(PE * sizeof(float2));
    float*  loT      = (float*) alloc(PE * sizeof(float));
    float*  upT      = (float*) alloc(PE * sizeof(float));
    float*  Ack      = (float*) alloc(C_CLS * K_MIX * sizeof(float));
    float*  const_ck = (float*) alloc(C_CLS * K_MIX * sizeof(float));
    int*    blockCnt = (int*)   alloc(HIST_BLOCKS * C_CLS * sizeof(int));
    int*    idxSorted= (int*)   alloc(N_PTS * sizeof(int));
    int*    classOff = (int*)   alloc((C_CLS + 1) * sizeof(int));
    float*  invden   = (float*) alloc(C_CLS * sizeof(float));
    float*  partials = (float*) alloc(C_CLS * MAIN_BPC * sizeof(float));

    k_prep<<<C_CLS * K_MIX + HIST_BLOCKS, 256, 0, stream>>>(
        mu, lower, upper, sigma, y, abT, loT, upT, Ack, blockCnt);
    k_scatter<<<HIST_BLOCKS, 256, 0, stream>>>(
        y, blockCnt, logits, Ack, idxSorted, classOff, invden, const_ck);
    k_main<<<C_CLS * MAIN_BPC, 256, 0, stream>>>(
        X, resp, abT, loT, upT, const_ck, classOff, invden, idxSorted, eta, partials);
    k_final<<<1, 256, 0, stream>>>(partials, out);
}